// Round 6
// baseline (189.083 us; speedup 1.0000x reference)
//
#include <hip/hip_runtime.h>
#include <math.h>

#define B 16
#define NAV 36
#define HIM 120
#define WIM 160
#define RH 512
#define NF 4
#define AE 37

// ---------------- workspace layout (floats) ----------------
// attn   : [B*NAV]            @ 0        (576)
// dfa    : [B*NF]             @ 576      (64)
// vf_raw : [2][B][3][12]      @ 640      (1152)
// y1     : [2][B][64][269]    @ 1792     (550912)   (dead after k_tail)
// cat    : [B][589]           @ 1792     (9424)     (aliases y1; written by k_vf)
// pano   : [B][360][1920]     @ 552704   (11059200)

__device__ __forceinline__ float rfl(float x) {
  return __int_as_float(__builtin_amdgcn_readfirstlane(__float_as_int(x)));
}

// ============ kernel 1: attn softmax + dynamic-filter MLP ============
__global__ __launch_bounds__(128) void k_head(
    const float* __restrict__ nnf, const float* __restrict__ ctx,
    const float* __restrict__ fc1w, const float* __restrict__ fc1b,
    const float* __restrict__ fc2w, const float* __restrict__ fc2b,
    float* __restrict__ attn, float* __restrict__ dfa) {
  int b = blockIdx.x;
  int t = threadIdx.x;  // 128 threads
  __shared__ float s_ctx[RH];
  __shared__ float s_v[NAV];
  __shared__ float s_hid[128];
  __shared__ float s_l[NF];
  __shared__ float s_inv[2];

  if (t < NAV) s_v[t] = nnf[b * NAV + t];
  for (int k = t; k < RH; k += 128) s_ctx[k] = ctx[b * RH + k];
  __syncthreads();

  if (t == 0) {
    float m = -1e30f;
    for (int i = 0; i < NAV; i++) m = fmaxf(m, s_v[i]);
    float s = 0.f;
    for (int i = 0; i < NAV; i++) { s_v[i] = expf(s_v[i] - m); s += s_v[i]; }
    s_inv[0] = 1.0f / s;
  }
  float acc = fc1b[t];
  const float* wr = fc1w + t * RH;
  for (int k = 0; k < RH; k++) acc += s_ctx[k] * wr[k];
  s_hid[t] = fmaxf(acc, 0.0f);
  __syncthreads();

  if (t < NAV) attn[b * NAV + t] = s_v[t] * s_inv[0];
  if (t < NF) {
    float a = fc2b[t];
    const float* w2 = fc2w + t * 128;
    for (int k = 0; k < 128; k++) a += s_hid[k] * w2[k];
    s_l[t] = a;
  }
  __syncthreads();
  if (t == 0) {
    float m = fmaxf(fmaxf(s_l[0], s_l[1]), fmaxf(s_l[2], s_l[3]));
    float s = 0.f;
    for (int f = 0; f < NF; f++) { s_l[f] = expf(s_l[f] - m); s += s_l[f]; }
    s_inv[1] = 1.0f / s;
  }
  __syncthreads();
  if (t < NF) dfa[b * NF + t] = s_l[t] * s_inv[1];
}

// ============ kernel 2: fused conv1 + attn-scale + dynamic conv -> pano ============
// TH=8 output rows x 160 cols of one (b,i) plane per block.
// LDW=172 floats (688B = 12 banks mod 32 -> rows have distinct bank phase;
// 172%4==0 keeps b128 alignment). Only pano rows with row%5==0 are consumed
// by conv2_1 (row = 5*oy+10*ky), so the out stage is predicated on
// (y0+dy)%5==0: 5x fewer out FMAs and 5x fewer pano writes.
#define TH 8
#define LDW 172
__global__ __launch_bounds__(256) void k_conv(
    const float* __restrict__ draw, const float* __restrict__ dclip,
    const float* __restrict__ obj,
    const float* __restrict__ c1w, const float* __restrict__ c1b,
    const float* __restrict__ dynf,
    const float* __restrict__ attn, const float* __restrict__ dfa,
    float* __restrict__ pano) {
  __shared__ __align__(16) float s_A[32 * LDW];  // raw[16][LDW] @0, clip[16][LDW] @16*LDW
  __shared__ float s_w1[50];
  __shared__ float s_k[50];
  float* s_raw = s_A;                // col j = gx+4 (gx -4..163 -> j 0..167)
  float* s_clip = s_A + 16 * LDW;
  // aliases (valid after raw/clip are dead):
  float* s_pd = s_A;                 // [12][LDW], col c = x+2
  float* s_po = s_A + 12 * LDW;      // [12][LDW], col j = x+4 (same layout as raw)

  int t = threadIdx.x;
  int bz = blockIdx.z;
  int b = bz / NAV, i = bz % NAV;
  int y0 = blockIdx.y * TH;
  const size_t plane = (size_t)(b * NAV + i) * HIM * WIM;
  const float* rawp = draw + plane;
  const float* clipp = dclip + plane;
  const float* objp = obj + plane;
  float attn_bi = attn[b * NAV + i];
  float bias = c1b[i];

  // phase 0a: weights
  if (t < 50) {
    s_w1[t] = c1w[i * 50 + t];
  } else if (t >= 64 && t < 114) {
    int j = t - 64;
    float a = 0.f;
    for (int f = 0; f < NF; f++) a += dfa[b * NF + f] * dynf[(f * NAV + i) * 50 + j];
    s_k[j] = a;
  }
  // phase 0b: zero halo cols (16 rows x 8 cols x 2 arrays = 256 writes)
  {
    int half = t >> 7;            // 0=raw, 1=clip
    int r = (t >> 3) & 15;
    int hc = t & 7;
    int col = hc < 4 ? hc : 160 + hc;  // 0..3, 164..167
    s_A[half * (16 * LDW) + r * LDW + col] = 0.f;
  }
  // phase 0c: interior staging, pure float4 (thread = (row, lane16))
  {
    int r = t >> 4;               // 0..15
    int lane16 = t & 15;
    int gy = y0 - 4 + r;
    bool yok = (gy >= 0 && gy < HIM);
    const float* gr = rawp + gy * WIM;
    const float* gc = clipp + gy * WIM;
#pragma unroll
    for (int jj = 0; jj < 3; jj++) {
      int g = lane16 + 16 * jj;   // float4 group, 0..47; valid < 40
      bool act = (g < 40);
      float4 vr = {0.f, 0.f, 0.f, 0.f}, vc = {0.f, 0.f, 0.f, 0.f};
      if (act && yok) {
        vr = *(const float4*)(gr + 4 * g);
        vc = *(const float4*)(gc + 4 * g);
      }
      if (act) {
        *(float4*)&s_raw[r * LDW + 4 + 4 * g] = vr;
        *(float4*)&s_clip[r * LDW + 4 + 4 * g] = vc;
      }
    }
  }
  __syncthreads();

  // phase 2a: issue obj loads early (consumed after next barrier)
  float4 pol[2];
  int por[2], pog[2];
  bool poa[2];
#pragma unroll
  for (int jj = 0; jj < 2; jj++) {
    int idx = t + 256 * jj;       // [0,512); valid < 480 = 12 rows * 40 groups
    bool act = (idx < 480);
    int r2 = idx / 40, g = idx - 40 * r2;
    int gy = y0 - 2 + r2;
    float4 v = {0.f, 0.f, 0.f, 0.f};
    if (act && gy >= 0 && gy < HIM) v = *(const float4*)(objp + gy * WIM + 4 * g);
    pol[jj] = v; por[jj] = r2; pog[jj] = g; poa[jj] = act;
  }

  // phase 2b: pd compute into registers (246 threads: 6 row-pairs x 41 groups)
  float pdv[2][4];
  int rp = 0, gq = 0;
  bool pact = (t < 246);
  if (pact) { rp = t / 41; gq = t - 41 * rp; }
  {
    float w1s[50];
#pragma unroll
    for (int k = 0; k < 50; k++) w1s[k] = rfl(s_w1[k]);

    float acc[2][4];
#pragma unroll
    for (int o = 0; o < 2; o++)
#pragma unroll
      for (int co = 0; co < 4; co++) acc[o][co] = 0.f;

    if (pact) {
      int cc0 = 4 * gq;
#pragma unroll
      for (int rr = 0; rr < 6; rr++) {
        int s = 2 * rp + rr;
        float v[8], u[8];
        *(float4*)&v[0] = *(const float4*)&s_raw[s * LDW + cc0];
        *(float4*)&v[4] = *(const float4*)&s_raw[s * LDW + cc0 + 4];
        *(float4*)&u[0] = *(const float4*)&s_clip[s * LDW + cc0];
        *(float4*)&u[4] = *(const float4*)&s_clip[s * LDW + cc0 + 4];
#pragma unroll
        for (int o = 0; o < 2; o++) {
          int ky = rr - o;
          if (ky >= 0 && ky < 5) {
#pragma unroll
            for (int kx = 0; kx < 5; kx++) {
              float w0 = w1s[ky * 5 + kx], w1 = w1s[25 + ky * 5 + kx];
#pragma unroll
              for (int co = 0; co < 4; co++)
                acc[o][co] += v[co + kx] * w0 + u[co + kx] * w1;
            }
          }
        }
      }
#pragma unroll
      for (int o = 0; o < 2; o++) {
        int r = 2 * rp + o;
        int y = y0 - 2 + r;
        bool yok = (y >= 0 && y < HIM);
#pragma unroll
        for (int co = 0; co < 4; co++) {
          int x = 4 * gq + co - 2;
          bool ok = yok && (x >= 0) && (x < WIM);
          pdv[o][co] = ok ? (bias + acc[o][co]) * attn_bi : 0.f;
        }
      }
    }
  }
  __syncthreads();  // raw/clip now dead

  // phase 4: write pd + scaled po into aliased LDS (float4, 16B lane-stride)
  if (pact) {
#pragma unroll
    for (int o = 0; o < 2; o++) {
      float4 p4 = {pdv[o][0], pdv[o][1], pdv[o][2], pdv[o][3]};
      *(float4*)&s_pd[(2 * rp + o) * LDW + 4 * gq] = p4;
    }
  }
#pragma unroll
  for (int jj = 0; jj < 2; jj++) {
    if (poa[jj]) {
      float4 v = pol[jj];
      v.x *= attn_bi; v.y *= attn_bi; v.z *= attn_bi; v.w *= attn_bi;
      *(float4*)&s_po[por[jj] * LDW + 4 + 4 * pog[jj]] = v;
    }
  }
  __syncthreads();

  // phase 6: out stage, only rows with (pano row)%5==0 are ever read by conv2_1
  {
    float ks[50];
#pragma unroll
    for (int k = 0; k < 50; k++) ks[k] = rfl(s_k[k]);

    int dy = t >> 5, gg = t & 31;
    if (((y0 + dy) % 5) == 0) {
      int x0 = 5 * gg;
      float a0 = 0.f, a1 = 0.f, a2 = 0.f, a3 = 0.f, a4 = 0.f;
#pragma unroll
      for (int ky = 0; ky < 5; ky++) {
        const float* pr = &s_pd[(dy + ky) * LDW + x0];       // pd col = x0 + (kx+j)
        const float* ob = &s_po[(dy + ky) * LDW + x0 + 2];   // po col = x0+2 + (kx+j)
        float p[9], o9[9];
#pragma unroll
        for (int jj = 0; jj < 9; jj++) { p[jj] = pr[jj]; o9[jj] = ob[jj]; }
#pragma unroll
        for (int kx = 0; kx < 5; kx++) {
          float k1 = ks[ky * 5 + kx], k2 = ks[25 + ky * 5 + kx];
          a0 += p[kx] * k1 + o9[kx] * k2;
          a1 += p[kx + 1] * k1 + o9[kx + 1] * k2;
          a2 += p[kx + 2] * k1 + o9[kx + 2] * k2;
          a3 += p[kx + 3] * k1 + o9[kx + 3] * k2;
          a4 += p[kx + 4] * k1 + o9[kx + 4] * k2;
        }
      }
      int q = i / 12, cw = i % 12;
      float* outp = pano + (size_t)b * 360 * 1920 +
                    (size_t)((2 - q) * HIM + y0 + dy) * 1920 + cw * WIM + x0;
      outp[0] = a0; outp[1] = a1; outp[2] = a2; outp[3] = a3; outp[4] = a4;
    }
  }
}

// ============ kernel 3: conv2_1, both roll paths, LDS row staging ============
__global__ __launch_bounds__(256) void k_c21(
    const float* __restrict__ pano, const float* __restrict__ w21,
    const float* __restrict__ b21, float* __restrict__ y1) {
  __shared__ float s_rows[5][1920];
  int t = threadIdx.x;
  int b = blockIdx.x, oy = blockIdx.y;
  const float* pp = pano + (size_t)b * 691200;
  for (int tt = t; tt < 2400; tt += 256) {
    int ky = tt / 480, g = tt % 480;
    int row = 5 * oy + 10 * ky;
    *(float4*)&s_rows[ky][4 * g] = *(const float4*)&pp[(size_t)row * 1920 + 4 * g];
  }
  float w[25];
#pragma unroll
  for (int k = 0; k < 25; k++) w[k] = w21[k];
  float bb = b21[0];
  __syncthreads();
  for (int tt = t; tt < 538; tt += 256) {
    int p = tt / 269, ox = tt % 269;
    int shift = p ? 1760 : 0;  // roll by +160 cols
    float acc = bb;
#pragma unroll
    for (int ky = 0; ky < 5; ky++)
#pragma unroll
      for (int kx = 0; kx < 5; kx++) {
        int X = 7 * ox + 10 * kx + shift;
        if (X >= 1920) X -= 1920;
        acc += w[ky * 5 + kx] * s_rows[ky][X];
      }
    y1[((size_t)(p * B + b) * 64 + oy) * 269 + ox] = acc;
  }
}

// ============ kernel 4: avgpool(3,3)/3 -> conv2_2 -> avgpool(3,9)/3 ============
__global__ __launch_bounds__(256) void k_tail(
    const float* __restrict__ y1, const float* __restrict__ w22,
    const float* __restrict__ b22, float* __restrict__ vf_raw) {
  __shared__ float s_y2[21][90];
  __shared__ float s_y3[10][44];
  int t = threadIdx.x;
  int pb = blockIdx.x;  // p*B+b
  const float* yp = y1 + (size_t)pb * 64 * 269;
  for (int idx = t; idx < 21 * 89; idx += 256) {
    int py = idx / 89, px = idx % 89;
    float s = 0.f;
    for (int dy = 0; dy < 3; dy++)
      for (int dx = 0; dx < 3; dx++)
        s += yp[(3 * py + dy) * 269 + 3 * px + dx];
    s_y2[py][px] = s * (1.0f / 9.0f);
  }
  __syncthreads();
  for (int idx = t; idx < 10 * 43; idx += 256) {
    int qy = idx / 43, qx = idx % 43;
    float a = b22[0];
#pragma unroll
    for (int ky = 0; ky < 3; ky++)
#pragma unroll
      for (int kx = 0; kx < 3; kx++)
        a += w22[ky * 3 + kx] * s_y2[2 * qy + ky][2 * qx + 2 * kx];
    s_y3[qy][qx] = a;
  }
  __syncthreads();
  if (t < 36) {
    int uy = t / 12, ux = t % 12;
    float s = 0.f;
    for (int dy = 0; dy < 3; dy++)
      for (int dx = 0; dx < 9; dx++)
        s += s_y3[3 * uy + dy][3 * ux + dx];
    vf_raw[pb * 36 + t] = s * (1.0f / 27.0f);
  }
}

// ============ kernel 5: vf combine/softmax, nav_mask, cat assembly ============
__global__ __launch_bounds__(256) void k_vf(
    const float* __restrict__ vf_raw, const int* __restrict__ nav_idx,
    const float* __restrict__ dfa, const float* __restrict__ ctx,
    const float* __restrict__ pre,
    float* __restrict__ out_vf, float* __restrict__ out_mask,
    float* __restrict__ cat) {
  int b = blockIdx.x;
  int t = threadIdx.x;  // 256
  __shared__ float s_v[36];
  __shared__ float s_inv;
  if (t < 36) {
    int u = t / 12, x = t % 12;
    float v1 = vf_raw[(0 * B + b) * 36 + (2 - u) * 12 + x];
    float v2 = vf_raw[(1 * B + b) * 36 + (2 - u) * 12 + (x + 1) % 12];
    s_v[t] = 0.5f * (v1 + v2) * 0.1f;  // /TEMP
  }
  __syncthreads();
  if (t == 0) {
    float m = -1e30f;
    for (int i = 0; i < 36; i++) m = fmaxf(m, s_v[i]);
    float s = 0.f;
    for (int i = 0; i < 36; i++) { s_v[i] = expf(s_v[i] - m); s += s_v[i]; }
    s_inv = 1.0f / s;
  }
  __syncthreads();
  if (t < 36) s_v[t] *= s_inv;  // normalized vf
  __syncthreads();
  if (t < 36) {
    out_vf[b * 36 + t] = s_v[t];
    float m = 0.f;
    for (int e = 0; e < 8; e++)
      if (nav_idx[b * 8 + e] == t) m = 1.0f;
    out_mask[b * 36 + t] = m;
  }
  // assemble concat row for the LSTM
  float* cb = cat + b * 589;
  for (int k = t; k < 589; k += 256) {
    float v;
    if (k < 512) v = ctx[b * 512 + k];
    else if (k < 548) v = s_v[k - 512];
    else if (k < 552) v = dfa[b * 4 + (k - 548)];
    else v = pre[b * 37 + (k - 552)];
    cb[k] = v;
  }
}

// ============ kernel 6: LSTM cell (512 blocks: one hidden unit each) ============
// 256 threads = 4 gates x 16 batches x 4 k-chunks; shuffle-reduce over chunks.
__global__ __launch_bounds__(256) void k_lstm(
    const float* __restrict__ cat, const float* __restrict__ h0,
    const float* __restrict__ c0,
    const float* __restrict__ wih, const float* __restrict__ whh,
    const float* __restrict__ bih, const float* __restrict__ bhh,
    float* __restrict__ h1, float* __restrict__ c1) {
  __shared__ float s_g[4][16];
  int t = threadIdx.x;
  int u = blockIdx.x;
  int gate = t >> 6, b = (t >> 2) & 15, kc = t & 3;
  int j = (gate << 9) + u;
  const float* wi = wih + (size_t)j * 589;
  const float* cb = cat + b * 589;
  float acc = 0.f;
  int k0 = kc * 148;
  int k1 = k0 + 148 > 589 ? 589 : k0 + 148;
  for (int k = k0; k < k1; k++) acc += cb[k] * wi[k];
  const float* wh = whh + (size_t)j * 512;
  const float* hb = h0 + b * 512;
  int m0 = kc * 128;
#pragma unroll 4
  for (int k = m0; k < m0 + 128; k++) acc += hb[k] * wh[k];
  acc += __shfl_xor(acc, 1);
  acc += __shfl_xor(acc, 2);
  if (kc == 0) s_g[gate][b] = acc + bih[j] + bhh[j];
  __syncthreads();
  if (t < 16) {
    float gi = s_g[0][t], gf = s_g[1][t], gg = s_g[2][t], go = s_g[3][t];
    float c_old = c0[t * 512 + u];
    float si = 1.0f / (1.0f + expf(-gi));
    float sf = 1.0f / (1.0f + expf(-gf));
    float so = 1.0f / (1.0f + expf(-go));
    float cn = sf * c_old + si * tanhf(gg);
    h1[t * 512 + u] = so * tanhf(cn);
    c1[t * 512 + u] = cn;
  }
}

extern "C" void kernel_launch(void* const* d_in, const int* in_sizes, int n_in,
                              void* d_out, int out_size, void* d_ws, size_t ws_size,
                              hipStream_t stream) {
  const float* depth_raw  = (const float*)d_in[0];
  const float* depth_clip = (const float*)d_in[1];
  const float* obj_feat   = (const float*)d_in[2];
  const float* nnf        = (const float*)d_in[3];
  const float* pre        = (const float*)d_in[4];
  const float* h0         = (const float*)d_in[5];
  const float* c0         = (const float*)d_in[6];
  const float* ctx        = (const float*)d_in[7];
  const int*   nav_idx    = (const int*)d_in[8];
  const float* c1w        = (const float*)d_in[9];
  const float* c1b        = (const float*)d_in[10];
  const float* fc1w       = (const float*)d_in[11];
  const float* fc1b       = (const float*)d_in[12];
  const float* fc2w       = (const float*)d_in[13];
  const float* fc2b       = (const float*)d_in[14];
  const float* dynf       = (const float*)d_in[15];
  const float* w21        = (const float*)d_in[16];
  const float* b21        = (const float*)d_in[17];
  const float* w22        = (const float*)d_in[18];
  const float* b22        = (const float*)d_in[19];
  const float* wih        = (const float*)d_in[20];
  const float* whh        = (const float*)d_in[21];
  const float* bih        = (const float*)d_in[22];
  const float* bhh        = (const float*)d_in[23];

  float* ws = (float*)d_ws;
  float* attn   = ws;
  float* dfa    = ws + 576;
  float* vf_raw = ws + 640;
  float* y1     = ws + 1792;
  float* cat    = ws + 1792;     // aliases y1 (y1 dead after k_tail)
  float* pano   = ws + 552704;

  float* out = (float*)d_out;
  float* out_h1   = out;
  float* out_c1   = out + 8192;
  float* out_vf   = out + 16384;
  float* out_mask = out + 16960;

  k_head<<<B, 128, 0, stream>>>(nnf, ctx, fc1w, fc1b, fc2w, fc2b, attn, dfa);
  k_conv<<<dim3(1, 15, B * NAV), 256, 0, stream>>>(depth_raw, depth_clip, obj_feat,
                                                   c1w, c1b, dynf, attn, dfa, pano);
  k_c21<<<dim3(B, 64), 256, 0, stream>>>(pano, w21, b21, y1);
  k_tail<<<2 * B, 256, 0, stream>>>(y1, w22, b22, vf_raw);
  k_vf<<<B, 256, 0, stream>>>(vf_raw, nav_idx, dfa, ctx, pre, out_vf, out_mask, cat);
  k_lstm<<<RH, 256, 0, stream>>>(cat, h0, c0, wih, whh, bih, bhh, out_h1, out_c1);
}

// Round 7
// 167.585 us; speedup vs baseline: 1.1283x; 1.1283x over previous
//
#include <hip/hip_runtime.h>
#include <math.h>

#define B 16
#define NAV 36
#define HIM 120
#define WIM 160
#define RH 512
#define NF 4
#define AE 37

// ---------------- workspace layout (floats) ----------------
// attn   : [B*NAV]            @ 0        (576)
// dfa    : [B*NF]             @ 576      (64)
// y1     : [2][B][64][269]    @ 1792     (550912)
// cpano  : [B][72][1920]      @ 552704   (2211840)   compact pano (rows%5==0 only)

__device__ __forceinline__ float rfl(float x) {
  return __int_as_float(__builtin_amdgcn_readfirstlane(__float_as_int(x)));
}

// ============ kernel 1: attn softmax + dynamic-filter MLP ============
__global__ __launch_bounds__(128) void k_head(
    const float* __restrict__ nnf, const float* __restrict__ ctx,
    const float* __restrict__ fc1w, const float* __restrict__ fc1b,
    const float* __restrict__ fc2w, const float* __restrict__ fc2b,
    float* __restrict__ attn, float* __restrict__ dfa) {
  int b = blockIdx.x;
  int t = threadIdx.x;  // 128 threads
  __shared__ float s_ctx[RH];
  __shared__ float s_v[NAV];
  __shared__ float s_hid[128];
  __shared__ float s_l[NF];
  __shared__ float s_inv[2];

  if (t < NAV) s_v[t] = nnf[b * NAV + t];
  for (int k = t; k < RH; k += 128) s_ctx[k] = ctx[b * RH + k];
  __syncthreads();

  if (t == 0) {
    float m = -1e30f;
    for (int i = 0; i < NAV; i++) m = fmaxf(m, s_v[i]);
    float s = 0.f;
    for (int i = 0; i < NAV; i++) { s_v[i] = expf(s_v[i] - m); s += s_v[i]; }
    s_inv[0] = 1.0f / s;
  }
  float acc = fc1b[t];
  const float* wr = fc1w + t * RH;
  for (int k = 0; k < RH; k++) acc += s_ctx[k] * wr[k];
  s_hid[t] = fmaxf(acc, 0.0f);
  __syncthreads();

  if (t < NAV) attn[b * NAV + t] = s_v[t] * s_inv[0];
  if (t < NF) {
    float a = fc2b[t];
    const float* w2 = fc2w + t * 128;
    for (int k = 0; k < 128; k++) a += s_hid[k] * w2[k];
    s_l[t] = a;
  }
  __syncthreads();
  if (t == 0) {
    float m = fmaxf(fmaxf(s_l[0], s_l[1]), fmaxf(s_l[2], s_l[3]));
    float s = 0.f;
    for (int f = 0; f < NF; f++) { s_l[f] = expf(s_l[f] - m); s += s_l[f]; }
    s_inv[1] = 1.0f / s;
  }
  __syncthreads();
  if (t < NF) dfa[b * NF + t] = s_l[t] * s_inv[1];
}

// ============ kernel 2: persistent fused conv1+scale+dynconv -> compact pano ============
// 1152 blocks = (b, i, half). Each block loops 7-8 y-tiles of 8 rows with a
// software pipeline: [write staged regs->LDS | issue next-tile + obj loads |
// barrier | pd compute | write pd/po (separate LDS region) | barrier | out].
// Out stage computes only pano rows %5==0 (the only rows conv2_1 reads),
// balanced across threads, writing a compact [B][72][1920] pano.
#define LDW 192
__global__ __launch_bounds__(256) void k_conv(
    const float* __restrict__ draw, const float* __restrict__ dclip,
    const float* __restrict__ obj,
    const float* __restrict__ c1w, const float* __restrict__ c1b,
    const float* __restrict__ dynf,
    const float* __restrict__ attn, const float* __restrict__ dfa,
    float* __restrict__ cpano) {
  __shared__ __align__(16) float s_raw[16 * LDW];   // col j = gx+4
  __shared__ __align__(16) float s_clip[16 * LDW];
  __shared__ __align__(16) float s_pd[12 * LDW];    // col c = x+2
  __shared__ __align__(16) float s_po[12 * LDW];    // col j = x+4
  __shared__ float s_w1[50];
  __shared__ float s_k[50];

  int t = threadIdx.x;
  int bz = blockIdx.x;
  int half = bz & 1;
  int pi = bz >> 1;
  int b = pi / NAV, i = pi - b * NAV;
  int ybase = half * 64;
  int NT = half ? 7 : 8;

  const size_t plane = (size_t)(b * NAV + i) * HIM * WIM;
  const float* rawp = draw + plane;
  const float* clipp = dclip + plane;
  const float* objp = obj + plane;
  float attn_bi = attn[b * NAV + i];
  float bias = c1b[i];
  int q = i / 12, cw = i - 12 * q;
  float* cpb = cpano + ((size_t)b * 72 + (2 - q) * 24) * 1920 + cw * WIM;

  // prologue: weights into LDS
  if (t < 50) {
    s_w1[t] = c1w[i * 50 + t];
  } else if (t >= 64 && t < 114) {
    int j = t - 64;
    float a = 0.f;
    for (int f = 0; f < NF; f++) a += dfa[b * NF + f] * dynf[(f * NAV + i) * 50 + j];
    s_k[j] = a;
  }
  // zero halo cols of raw/clip (never touched by per-tile staging)
  { int ha = t >> 7, r = (t >> 3) & 15, hc = t & 7;
    int col = hc < 4 ? hc : 160 + hc;
    (ha ? s_clip : s_raw)[r * LDW + col] = 0.f; }
  // zero halo cols of po
  if (t < 96) { int r = t >> 3, hc = t & 7;
    int col = hc < 4 ? hc : 160 + hc;
    s_po[r * LDW + col] = 0.f; }

  // per-thread constant mappings (no divisions inside the loop)
  int sr = t >> 4, sl = t & 15;        // staging: row, lane16
  int rp = 0, gq = 0; bool pact = (t < 246);
  if (pact) { rp = t / 41; gq = t - 41 * rp; }
  int orow[2], og[2]; bool oact[2];
#pragma unroll
  for (int jj = 0; jj < 2; jj++) {
    int idx = t + 256 * jj;
    oact[jj] = idx < 480;
    orow[jj] = idx / 40;
    og[jj] = idx - 40 * orow[jj];
  }

  // prologue prefetch: tile 0 into regs
  float4 pr_r[3], pr_c[3];
  {
    int gy = ybase - 4 + sr;
    bool yok = (gy >= 0 && gy < HIM);
    const float* gr = rawp + gy * WIM;
    const float* gc = clipp + gy * WIM;
#pragma unroll
    for (int jj = 0; jj < 3; jj++) {
      int g = sl + 16 * jj;
      float4 vr = {0.f, 0.f, 0.f, 0.f}, vc = {0.f, 0.f, 0.f, 0.f};
      if (g < 40 && yok) { vr = *(const float4*)(gr + 4 * g); vc = *(const float4*)(gc + 4 * g); }
      pr_r[jj] = vr; pr_c[jj] = vc;
    }
  }
  __syncthreads();  // weights + halo zeros visible

  // conv1 weights -> SGPRs, once per block
  float w1s[50];
#pragma unroll
  for (int k = 0; k < 50; k++) w1s[k] = rfl(s_w1[k]);

  for (int tt = 0; tt < NT; tt++) {
    int y0 = ybase + (tt << 3);
    // A: staged regs -> LDS (16B lane-stride float4)
#pragma unroll
    for (int jj = 0; jj < 3; jj++) {
      int g = sl + 16 * jj;
      if (g < 40) {
        *(float4*)&s_raw[sr * LDW + 4 + 4 * g] = pr_r[jj];
        *(float4*)&s_clip[sr * LDW + 4 + 4 * g] = pr_c[jj];
      }
    }
    // B: issue next-tile prefetch (hidden under this tile's compute)
    if (tt + 1 < NT) {
      int gy = y0 + 4 + sr;
      bool yok = (gy >= 0 && gy < HIM);
      const float* gr = rawp + gy * WIM;
      const float* gc = clipp + gy * WIM;
#pragma unroll
      for (int jj = 0; jj < 3; jj++) {
        int g = sl + 16 * jj;
        float4 vr = {0.f, 0.f, 0.f, 0.f}, vc = {0.f, 0.f, 0.f, 0.f};
        if (g < 40 && yok) { vr = *(const float4*)(gr + 4 * g); vc = *(const float4*)(gc + 4 * g); }
        pr_r[jj] = vr; pr_c[jj] = vc;
      }
    }
    // C: issue obj loads for this tile (consumed after pd compute)
    float4 pol[2];
#pragma unroll
    for (int jj = 0; jj < 2; jj++) {
      int gy = y0 - 2 + orow[jj];
      float4 v = {0.f, 0.f, 0.f, 0.f};
      if (oact[jj] && gy >= 0 && gy < HIM)
        v = *(const float4*)(objp + gy * WIM + 4 * og[jj]);
      pol[jj] = v;
    }
    __syncthreads();

    // D: pd compute into registers (246 threads: 6 row-pairs x 41 col-groups)
    float pdv[2][4];
    {
      float acc[2][4];
#pragma unroll
      for (int o = 0; o < 2; o++)
#pragma unroll
        for (int co = 0; co < 4; co++) acc[o][co] = 0.f;
      if (pact) {
        int cc0 = 4 * gq;
#pragma unroll
        for (int rr = 0; rr < 6; rr++) {
          int s = 2 * rp + rr;
          float v[8], u[8];
          *(float4*)&v[0] = *(const float4*)&s_raw[s * LDW + cc0];
          *(float4*)&v[4] = *(const float4*)&s_raw[s * LDW + cc0 + 4];
          *(float4*)&u[0] = *(const float4*)&s_clip[s * LDW + cc0];
          *(float4*)&u[4] = *(const float4*)&s_clip[s * LDW + cc0 + 4];
#pragma unroll
          for (int o = 0; o < 2; o++) {
            int ky = rr - o;
            if (ky >= 0 && ky < 5) {
#pragma unroll
              for (int kx = 0; kx < 5; kx++) {
                float w0 = w1s[ky * 5 + kx], w1 = w1s[25 + ky * 5 + kx];
#pragma unroll
                for (int co = 0; co < 4; co++)
                  acc[o][co] += v[co + kx] * w0 + u[co + kx] * w1;
              }
            }
          }
        }
#pragma unroll
        for (int o = 0; o < 2; o++) {
          int r = 2 * rp + o;
          int y = y0 - 2 + r;
          bool yok = (y >= 0 && y < HIM);
#pragma unroll
          for (int co = 0; co < 4; co++) {
            int x = 4 * gq + co - 2;
            bool ok = yok && (x >= 0) && (x < WIM);
            pdv[o][co] = ok ? (bias + acc[o][co]) * attn_bi : 0.f;
          }
        }
      }
    }
    // E: write pd + scaled po (separate LDS region -> no extra barrier)
    if (pact) {
#pragma unroll
      for (int o = 0; o < 2; o++) {
        float4 p4 = {pdv[o][0], pdv[o][1], pdv[o][2], pdv[o][3]};
        *(float4*)&s_pd[(2 * rp + o) * LDW + 4 * gq] = p4;
      }
    }
#pragma unroll
    for (int jj = 0; jj < 2; jj++) {
      if (oact[jj]) {
        float4 v = pol[jj];
        v.x *= attn_bi; v.y *= attn_bi; v.z *= attn_bi; v.w *= attn_bi;
        *(float4*)&s_po[orow[jj] * LDW + 4 + 4 * og[jj]] = v;
      }
    }
    __syncthreads();

    // F: out stage — only rows %5==0 (1-2 per tile), balanced over threads
    {
      float ksv[50];
#pragma unroll
      for (int k = 0; k < 50; k++) ksv[k] = s_k[k];
      int r5a = ((y0 + 4) / 5) * 5;      // first multiple of 5 in [y0, y0+8)
      int r5a5 = (y0 + 4) / 5;
      int nr = (r5a + 5 < y0 + 8) ? 2 : 1;
      int nitems = nr * 160;
#pragma unroll
      for (int pass = 0; pass < 2; pass++) {
        int it = t + 256 * pass;
        if (it < nitems) {
          int row1 = it >= 160 ? 1 : 0;
          int x = it - 160 * row1;
          int pdb = r5a + 5 * row1 - y0;   // 0..7: pd row base for taps
          float a = 0.f;
#pragma unroll
          for (int ky = 0; ky < 5; ky++) {
            const float* pr = &s_pd[(pdb + ky) * LDW + x];
            const float* ob = &s_po[(pdb + ky) * LDW + x + 2];
#pragma unroll
            for (int kx = 0; kx < 5; kx++)
              a += pr[kx] * ksv[ky * 5 + kx] + ob[kx] * ksv[25 + ky * 5 + kx];
          }
          int crow = r5a5 + row1;          // compact row within this q-band
          cpb[(size_t)crow * 1920 + x] = a;
        }
      }
    }
  }
}

// ============ kernel 3: conv2_1 on compact pano, both roll paths ============
__global__ __launch_bounds__(256) void k_c21(
    const float* __restrict__ cpano, const float* __restrict__ w21,
    const float* __restrict__ b21, float* __restrict__ y1) {
  __shared__ float s_rows[5][1920];
  int t = threadIdx.x;
  int b = blockIdx.x, oy = blockIdx.y;
  const float* pp = cpano + (size_t)b * 72 * 1920;
  for (int tt = t; tt < 2400; tt += 256) {
    int ky = tt / 480, g = tt - 480 * ky;
    // full-pano row 5*oy+10*ky -> compact row oy+2*ky
    *(float4*)&s_rows[ky][4 * g] = *(const float4*)&pp[(size_t)(oy + 2 * ky) * 1920 + 4 * g];
  }
  float w[25];
#pragma unroll
  for (int k = 0; k < 25; k++) w[k] = w21[k];
  float bb = b21[0];
  __syncthreads();
  for (int tt = t; tt < 538; tt += 256) {
    int p = tt / 269, ox = tt - 269 * p;
    int shift = p ? 1760 : 0;  // roll by +160 cols
    float acc = bb;
#pragma unroll
    for (int ky = 0; ky < 5; ky++)
#pragma unroll
      for (int kx = 0; kx < 5; kx++) {
        int X = 7 * ox + 10 * kx + shift;
        if (X >= 1920) X -= 1920;
        acc += w[ky * 5 + kx] * s_rows[ky][X];
      }
    y1[((size_t)(p * B + b) * 64 + oy) * 269 + ox] = acc;
  }
}

// ============ kernel 4: fused avgpool->conv2_2->avgpool (both paths) + vf ============
__global__ __launch_bounds__(256) void k_tailvf(
    const float* __restrict__ y1, const float* __restrict__ w22,
    const float* __restrict__ b22, const int* __restrict__ nav_idx,
    float* __restrict__ out_vf, float* __restrict__ out_mask) {
  __shared__ float s_y2[21][90];
  __shared__ float s_y3[10][44];
  __shared__ float s_vf2[2][36];
  __shared__ float s_v[36];
  __shared__ float s_inv;
  int t = threadIdx.x;
  int b = blockIdx.x;
  for (int p = 0; p < 2; p++) {
    const float* yp = y1 + (size_t)(p * B + b) * 64 * 269;
    for (int idx = t; idx < 21 * 89; idx += 256) {
      int py = idx / 89, px = idx - 89 * py;
      float s = 0.f;
      for (int dy = 0; dy < 3; dy++)
        for (int dx = 0; dx < 3; dx++)
          s += yp[(3 * py + dy) * 269 + 3 * px + dx];
      s_y2[py][px] = s * (1.0f / 9.0f);
    }
    __syncthreads();
    for (int idx = t; idx < 10 * 43; idx += 256) {
      int qy = idx / 43, qx = idx - 43 * qy;
      float a = b22[0];
#pragma unroll
      for (int ky = 0; ky < 3; ky++)
#pragma unroll
        for (int kx = 0; kx < 3; kx++)
          a += w22[ky * 3 + kx] * s_y2[2 * qy + ky][2 * qx + 2 * kx];
      s_y3[qy][qx] = a;
    }
    __syncthreads();
    if (t < 36) {
      int uy = t / 12, ux = t - 12 * uy;
      float s = 0.f;
      for (int dy = 0; dy < 3; dy++)
        for (int dx = 0; dx < 9; dx++)
          s += s_y3[3 * uy + dy][3 * ux + dx];
      s_vf2[p][t] = s * (1.0f / 27.0f);
    }
    __syncthreads();
  }
  if (t < 36) {
    int u = t / 12, x = t - 12 * u;
    float v1 = s_vf2[0][(2 - u) * 12 + x];
    float v2 = s_vf2[1][(2 - u) * 12 + (x + 1) % 12];
    s_v[t] = 0.5f * (v1 + v2) * 0.1f;  // /TEMP
  }
  __syncthreads();
  if (t == 0) {
    float m = -1e30f;
    for (int i = 0; i < 36; i++) m = fmaxf(m, s_v[i]);
    float s = 0.f;
    for (int i = 0; i < 36; i++) { s_v[i] = expf(s_v[i] - m); s += s_v[i]; }
    s_inv = 1.0f / s;
  }
  __syncthreads();
  if (t < 36) {
    out_vf[b * 36 + t] = s_v[t] * s_inv;
    float m = 0.f;
    for (int e = 0; e < 8; e++)
      if (nav_idx[b * 8 + e] == t) m = 1.0f;
    out_mask[b * 36 + t] = m;
  }
}

// ============ kernel 5: LSTM cell (R5-proven version) ============
__global__ __launch_bounds__(256) void k_lstm(
    const float* __restrict__ ctx, const float* __restrict__ vf,
    const float* __restrict__ dfa, const float* __restrict__ pre,
    const float* __restrict__ h0, const float* __restrict__ c0,
    const float* __restrict__ wih, const float* __restrict__ whh,
    const float* __restrict__ bih, const float* __restrict__ bhh,
    float* __restrict__ h1, float* __restrict__ c1) {
  __shared__ float s_cat[B][593];
  __shared__ float s_g[16][16];
  int t = threadIdx.x;
  int u0 = blockIdx.x * 4;
  for (int idx = t; idx < B * 589; idx += 256) {
    int b = idx / 589, k = idx - 589 * b;
    float v;
    if (k < 512) v = ctx[b * 512 + k];
    else if (k < 548) v = vf[b * 36 + (k - 512)];
    else if (k < 552) v = dfa[b * 4 + (k - 548)];
    else v = pre[b * 37 + (k - 552)];
    s_cat[b][k] = v;
  }
  __syncthreads();
  int b = t & 15;
  int slot = t >> 4;               // gate*4 + du
  int gate = slot >> 2, du = slot & 3;
  int j = gate * 512 + u0 + du;
  float acc = bih[j] + bhh[j];
  const float* wi = wih + (size_t)j * 589;
  for (int k = 0; k < 589; k++) acc += s_cat[b][k] * wi[k];
  const float* wh = whh + (size_t)j * 512;
  const float* hb = h0 + b * 512;
  for (int k = 0; k < 512; k++) acc += hb[k] * wh[k];
  s_g[slot][b] = acc;
  __syncthreads();
  if (t < 64) {
    int bb = t & 15, du2 = t >> 4;  // 0..3
    float gi = s_g[du2][bb], gf = s_g[4 + du2][bb];
    float gg = s_g[8 + du2][bb], go = s_g[12 + du2][bb];
    int u = u0 + du2;
    float c_old = c0[bb * 512 + u];
    float si = 1.0f / (1.0f + expf(-gi));
    float sf = 1.0f / (1.0f + expf(-gf));
    float so = 1.0f / (1.0f + expf(-go));
    float cn = sf * c_old + si * tanhf(gg);
    h1[bb * 512 + u] = so * tanhf(cn);
    c1[bb * 512 + u] = cn;
  }
}

extern "C" void kernel_launch(void* const* d_in, const int* in_sizes, int n_in,
                              void* d_out, int out_size, void* d_ws, size_t ws_size,
                              hipStream_t stream) {
  const float* depth_raw  = (const float*)d_in[0];
  const float* depth_clip = (const float*)d_in[1];
  const float* obj_feat   = (const float*)d_in[2];
  const float* nnf        = (const float*)d_in[3];
  const float* pre        = (const float*)d_in[4];
  const float* h0         = (const float*)d_in[5];
  const float* c0         = (const float*)d_in[6];
  const float* ctx        = (const float*)d_in[7];
  const int*   nav_idx    = (const int*)d_in[8];
  const float* c1w        = (const float*)d_in[9];
  const float* c1b        = (const float*)d_in[10];
  const float* fc1w       = (const float*)d_in[11];
  const float* fc1b       = (const float*)d_in[12];
  const float* fc2w       = (const float*)d_in[13];
  const float* fc2b       = (const float*)d_in[14];
  const float* dynf       = (const float*)d_in[15];
  const float* w21        = (const float*)d_in[16];
  const float* b21        = (const float*)d_in[17];
  const float* w22        = (const float*)d_in[18];
  const float* b22        = (const float*)d_in[19];
  const float* wih        = (const float*)d_in[20];
  const float* whh        = (const float*)d_in[21];
  const float* bih        = (const float*)d_in[22];
  const float* bhh        = (const float*)d_in[23];

  float* ws = (float*)d_ws;
  float* attn   = ws;
  float* dfa    = ws + 576;
  float* y1     = ws + 1792;
  float* cpano  = ws + 552704;

  float* out = (float*)d_out;
  float* out_h1   = out;
  float* out_c1   = out + 8192;
  float* out_vf   = out + 16384;
  float* out_mask = out + 16960;

  k_head<<<B, 128, 0, stream>>>(nnf, ctx, fc1w, fc1b, fc2w, fc2b, attn, dfa);
  k_conv<<<B * NAV * 2, 256, 0, stream>>>(depth_raw, depth_clip, obj_feat,
                                          c1w, c1b, dynf, attn, dfa, cpano);
  k_c21<<<dim3(B, 64), 256, 0, stream>>>(cpano, w21, b21, y1);
  k_tailvf<<<B, 256, 0, stream>>>(y1, w22, b22, nav_idx, out_vf, out_mask);
  k_lstm<<<128, 256, 0, stream>>>(ctx, out_vf, dfa, pre, h0, c0,
                                  wih, whh, bih, bhh, out_h1, out_c1);
}

// Round 8
// 149.741 us; speedup vs baseline: 1.2627x; 1.1192x over previous
//
#include <hip/hip_runtime.h>
#include <math.h>

#define B 16
#define NAV 36
#define HIM 120
#define WIM 160
#define RH 512
#define NF 4
#define AE 37

// ---------------- workspace layout (floats) ----------------
// attn   : [B*NAV]            @ 0        (576)
// dfa    : [B*NF]             @ 576      (64)
// y1     : [2][B][64][269]    @ 1792     (550912)
// cpano  : [B][72][1920]      @ 552704   (2211840)   compact pano (rows%5==0 only)

__device__ __forceinline__ float rfl(float x) {
  return __int_as_float(__builtin_amdgcn_readfirstlane(__float_as_int(x)));
}

// ============ kernel 1: attn softmax + dynamic-filter MLP ============
__global__ __launch_bounds__(128) void k_head(
    const float* __restrict__ nnf, const float* __restrict__ ctx,
    const float* __restrict__ fc1w, const float* __restrict__ fc1b,
    const float* __restrict__ fc2w, const float* __restrict__ fc2b,
    float* __restrict__ attn, float* __restrict__ dfa) {
  int b = blockIdx.x;
  int t = threadIdx.x;  // 128 threads
  __shared__ float s_ctx[RH];
  __shared__ float s_v[NAV];
  __shared__ float s_hid[128];
  __shared__ float s_l[NF];
  __shared__ float s_inv[2];

  if (t < NAV) s_v[t] = nnf[b * NAV + t];
  for (int k = t; k < RH; k += 128) s_ctx[k] = ctx[b * RH + k];
  __syncthreads();

  if (t == 0) {
    float m = -1e30f;
    for (int i = 0; i < NAV; i++) m = fmaxf(m, s_v[i]);
    float s = 0.f;
    for (int i = 0; i < NAV; i++) { s_v[i] = expf(s_v[i] - m); s += s_v[i]; }
    s_inv[0] = 1.0f / s;
  }
  float acc = fc1b[t];
  const float* wr = fc1w + t * RH;
  for (int k = 0; k < RH; k++) acc += s_ctx[k] * wr[k];
  s_hid[t] = fmaxf(acc, 0.0f);
  __syncthreads();

  if (t < NAV) attn[b * NAV + t] = s_v[t] * s_inv[0];
  if (t < NF) {
    float a = fc2b[t];
    const float* w2 = fc2w + t * 128;
    for (int k = 0; k < 128; k++) a += s_hid[k] * w2[k];
    s_l[t] = a;
  }
  __syncthreads();
  if (t == 0) {
    float m = fmaxf(fmaxf(s_l[0], s_l[1]), fmaxf(s_l[2], s_l[3]));
    float s = 0.f;
    for (int f = 0; f < NF; f++) { s_l[f] = expf(s_l[f] - m); s += s_l[f]; }
    s_inv[1] = 1.0f / s;
  }
  __syncthreads();
  if (t < NF) dfa[b * NF + t] = s_l[t] * s_inv[1];
}

// ============ kernel 2: persistent fused conv1+scale+dynconv -> compact pano ============
// 1152 blocks = (b, i, half). Half-strip = 60 rows, 6 tiles of ADVANCE 10:
// stage raw/clip rows y0-4..y0+9 (14), compute pd rows y0-2..y0+7 (10, zero
// recompute: each pd row feeds exactly one out row), emit out rows y0, y0+5
// (the only rows conv2_1 reads) into compact [B][72][1920] pano.
// Pipeline per tile: [regs->LDS | prefetch next | issue obj] bar [pd | write
// pd/po] bar [out]. LDW=172 (rows distinct bank phase), LDS 33.0KB -> 4 blk/CU.
#define LDW 172
__global__ __launch_bounds__(256) void k_conv(
    const float* __restrict__ draw, const float* __restrict__ dclip,
    const float* __restrict__ obj,
    const float* __restrict__ c1w, const float* __restrict__ c1b,
    const float* __restrict__ dynf,
    const float* __restrict__ attn, const float* __restrict__ dfa,
    float* __restrict__ cpano) {
  __shared__ __align__(16) float s_raw[14 * LDW];   // col j = gx+4, rows s=gy-(y0-4)
  __shared__ __align__(16) float s_clip[14 * LDW];
  __shared__ __align__(16) float s_pd[10 * LDW];    // col c = x+2, rows r=y-(y0-2)
  __shared__ __align__(16) float s_po[10 * LDW];    // col j = x+4
  __shared__ float s_w1[50];
  __shared__ float s_k[50];

  int t = threadIdx.x;
  int bz = blockIdx.x;
  int half = bz & 1;
  int pi = bz >> 1;
  int b = pi / NAV, i = pi - b * NAV;
  int ybase = 60 * half;

  const size_t plane = (size_t)(b * NAV + i) * HIM * WIM;
  const float* rawp = draw + plane;
  const float* clipp = dclip + plane;
  const float* objp = obj + plane;
  float attn_bi = attn[b * NAV + i];
  float bias = c1b[i];
  int q = i / 12, cw = i - 12 * q;
  float* cpb = cpano + ((size_t)b * 72 + (2 - q) * 24) * 1920 + cw * WIM;

  // prologue: weights into LDS
  if (t < 50) {
    s_w1[t] = c1w[i * 50 + t];
  } else if (t >= 64 && t < 114) {
    int j = t - 64;
    float a = 0.f;
    for (int f = 0; f < NF; f++) a += dfa[b * NF + f] * dynf[(f * NAV + i) * 50 + j];
    s_k[j] = a;
  }
  // zero halo cols (cols 0..3, 164..167) — written once, preserved all tiles
  if (t < 224) {  // raw/clip: 2 arrays x 14 rows x 8 cols
    int ha = t / 112, rem = t - 112 * ha;
    int r = rem >> 3, hc = rem & 7;
    int col = hc < 4 ? hc : 160 + hc;
    (ha ? s_clip : s_raw)[r * LDW + col] = 0.f;
  }
  if (t < 80) {   // po: 10 rows x 8 cols
    int r = t >> 3, hc = t & 7;
    int col = hc < 4 ? hc : 160 + hc;
    s_po[r * LDW + col] = 0.f;
  }

  // per-thread constant mappings (computed once)
  int prow[3], pg[3]; bool pra[3];      // staging: 560 float4 items = 14 rows x 40 groups
#pragma unroll
  for (int jj = 0; jj < 3; jj++) {
    int idx = t + 256 * jj;
    pra[jj] = idx < 560;
    prow[jj] = idx / 40;
    pg[jj] = idx - 40 * prow[jj];
  }
  int vrow[2], vg[2]; bool va[2];       // obj: 400 float4 items = 10 rows x 40 groups
#pragma unroll
  for (int jj = 0; jj < 2; jj++) {
    int idx = t + 256 * jj;
    va[jj] = idx < 400;
    vrow[jj] = idx / 40;
    vg[jj] = idx - 40 * vrow[jj];
  }
  int rp = 0, gq = 0; bool pact = (t < 205);   // pd: 5 row-pairs x 41 groups
  if (pact) { rp = t / 41; gq = t - 41 * rp; }

  // tile-0 prefetch into regs
  float4 pr_r[3], pr_c[3];
#pragma unroll
  for (int jj = 0; jj < 3; jj++) {
    int gy = ybase - 4 + prow[jj];
    bool ok = pra[jj] && gy >= 0 && gy < HIM;
    float4 vr = {0.f, 0.f, 0.f, 0.f}, vc = {0.f, 0.f, 0.f, 0.f};
    if (ok) { vr = *(const float4*)(rawp + gy * WIM + 4 * pg[jj]);
              vc = *(const float4*)(clipp + gy * WIM + 4 * pg[jj]); }
    pr_r[jj] = vr; pr_c[jj] = vc;
  }
  __syncthreads();

  // conv1 weights -> SGPR (block-uniform); dyn weights -> VGPR, once per block
  float w1s[50];
#pragma unroll
  for (int k = 0; k < 50; k++) w1s[k] = rfl(s_w1[k]);
  float ks[50];
#pragma unroll
  for (int k = 0; k < 50; k++) ks[k] = s_k[k];

  for (int tt = 0; tt < 6; tt++) {
    int y0 = ybase + 10 * tt;
    // A: staged regs -> LDS
#pragma unroll
    for (int jj = 0; jj < 3; jj++) {
      if (pra[jj]) {
        *(float4*)&s_raw[prow[jj] * LDW + 4 + 4 * pg[jj]] = pr_r[jj];
        *(float4*)&s_clip[prow[jj] * LDW + 4 + 4 * pg[jj]] = pr_c[jj];
      }
    }
    // B: prefetch next tile (latency hides under this tile's compute)
    if (tt < 5) {
#pragma unroll
      for (int jj = 0; jj < 3; jj++) {
        int gy = y0 + 6 + prow[jj];
        bool ok = pra[jj] && gy < HIM;
        float4 vr = {0.f, 0.f, 0.f, 0.f}, vc = {0.f, 0.f, 0.f, 0.f};
        if (ok) { vr = *(const float4*)(rawp + gy * WIM + 4 * pg[jj]);
                  vc = *(const float4*)(clipp + gy * WIM + 4 * pg[jj]); }
        pr_r[jj] = vr; pr_c[jj] = vc;
      }
    }
    // C: issue obj loads for this tile
    float4 pol[2];
#pragma unroll
    for (int jj = 0; jj < 2; jj++) {
      int gy = y0 - 2 + vrow[jj];
      float4 v = {0.f, 0.f, 0.f, 0.f};
      if (va[jj] && gy >= 0 && gy < HIM)
        v = *(const float4*)(objp + gy * WIM + 4 * vg[jj]);
      pol[jj] = v;
    }
    __syncthreads();

    // D: pd compute (205 threads: 5 row-pairs x 41 col-groups of 4)
    float pdv[2][4];
    {
      float acc[2][4];
#pragma unroll
      for (int o = 0; o < 2; o++)
#pragma unroll
        for (int co = 0; co < 4; co++) acc[o][co] = 0.f;
      if (pact) {
        int cc0 = 4 * gq;
#pragma unroll
        for (int rr = 0; rr < 6; rr++) {
          int s = 2 * rp + rr;
          float v[8], u[8];
          *(float4*)&v[0] = *(const float4*)&s_raw[s * LDW + cc0];
          *(float4*)&v[4] = *(const float4*)&s_raw[s * LDW + cc0 + 4];
          *(float4*)&u[0] = *(const float4*)&s_clip[s * LDW + cc0];
          *(float4*)&u[4] = *(const float4*)&s_clip[s * LDW + cc0 + 4];
#pragma unroll
          for (int o = 0; o < 2; o++) {
            int ky = rr - o;
            if (ky >= 0 && ky < 5) {
#pragma unroll
              for (int kx = 0; kx < 5; kx++) {
                float w0 = w1s[ky * 5 + kx], w1 = w1s[25 + ky * 5 + kx];
#pragma unroll
                for (int co = 0; co < 4; co++)
                  acc[o][co] += v[co + kx] * w0 + u[co + kx] * w1;
              }
            }
          }
        }
#pragma unroll
        for (int o = 0; o < 2; o++) {
          int r = 2 * rp + o;
          int y = y0 - 2 + r;
          bool yok = (y >= 0 && y < HIM);
#pragma unroll
          for (int co = 0; co < 4; co++) {
            int x = 4 * gq + co - 2;
            bool ok = yok && (x >= 0) && (x < WIM);
            pdv[o][co] = ok ? (bias + acc[o][co]) * attn_bi : 0.f;
          }
        }
      }
    }
    // E: write pd + scaled po
    if (pact) {
#pragma unroll
      for (int o = 0; o < 2; o++) {
        float4 p4 = {pdv[o][0], pdv[o][1], pdv[o][2], pdv[o][3]};
        *(float4*)&s_pd[(2 * rp + o) * LDW + 4 * gq] = p4;
      }
    }
#pragma unroll
    for (int jj = 0; jj < 2; jj++) {
      if (va[jj]) {
        float4 v = pol[jj];
        v.x *= attn_bi; v.y *= attn_bi; v.z *= attn_bi; v.w *= attn_bi;
        *(float4*)&s_po[vrow[jj] * LDW + 4 + 4 * vg[jj]] = v;
      }
    }
    __syncthreads();

    // F: out rows y0 (pd taps r=0..4) and y0+5 (r=5..9); 320 items
#pragma unroll
    for (int pass = 0; pass < 2; pass++) {
      int it = t + 256 * pass;
      if (it < 320) {
        int row1 = it >= 160 ? 1 : 0;
        int x = it - 160 * row1;
        float a = 0.f;
#pragma unroll
        for (int ky = 0; ky < 5; ky++) {
          const float* pr = &s_pd[(5 * row1 + ky) * LDW + x];
          const float* ob = &s_po[(5 * row1 + ky) * LDW + x + 2];
#pragma unroll
          for (int kx = 0; kx < 5; kx++)
            a += pr[kx] * ks[ky * 5 + kx] + ob[kx] * ks[25 + ky * 5 + kx];
        }
        cpb[(size_t)(12 * half + 2 * tt + row1) * 1920 + x] = a;
      }
    }
  }
}

// ============ kernel 3: conv2_1 on compact pano, both roll paths ============
__global__ __launch_bounds__(256) void k_c21(
    const float* __restrict__ cpano, const float* __restrict__ w21,
    const float* __restrict__ b21, float* __restrict__ y1) {
  __shared__ float s_rows[5][1920];
  int t = threadIdx.x;
  int b = blockIdx.x, oy = blockIdx.y;
  const float* pp = cpano + (size_t)b * 72 * 1920;
  for (int tt = t; tt < 2400; tt += 256) {
    int ky = tt / 480, g = tt - 480 * ky;
    // full-pano row 5*oy+10*ky -> compact row oy+2*ky
    *(float4*)&s_rows[ky][4 * g] = *(const float4*)&pp[(size_t)(oy + 2 * ky) * 1920 + 4 * g];
  }
  float w[25];
#pragma unroll
  for (int k = 0; k < 25; k++) w[k] = w21[k];
  float bb = b21[0];
  __syncthreads();
  for (int tt = t; tt < 538; tt += 256) {
    int p = tt / 269, ox = tt - 269 * p;
    int shift = p ? 1760 : 0;  // roll by +160 cols
    float acc = bb;
#pragma unroll
    for (int ky = 0; ky < 5; ky++)
#pragma unroll
      for (int kx = 0; kx < 5; kx++) {
        int X = 7 * ox + 10 * kx + shift;
        if (X >= 1920) X -= 1920;
        acc += w[ky * 5 + kx] * s_rows[ky][X];
      }
    y1[((size_t)(p * B + b) * 64 + oy) * 269 + ox] = acc;
  }
}

// ============ kernel 4: fused pools+conv2_2 (both paths in parallel) + vf ============
__global__ __launch_bounds__(512) void k_tailvf(
    const float* __restrict__ y1, const float* __restrict__ w22,
    const float* __restrict__ b22, const int* __restrict__ nav_idx,
    float* __restrict__ out_vf, float* __restrict__ out_mask) {
  __shared__ float s_y2[2][21][90];
  __shared__ float s_y3[2][10][44];
  __shared__ float s_vf2[2][36];
  __shared__ float s_v[36];
  __shared__ float s_inv;
  int t = threadIdx.x;           // 512: [0,256)=path0, [256,512)=path1
  int b = blockIdx.x;
  int p = t >> 8, tp = t & 255;
  const float* yp = y1 + (size_t)(p * B + b) * 64 * 269;
  for (int idx = tp; idx < 21 * 89; idx += 256) {
    int py = idx / 89, px = idx - 89 * py;
    float s = 0.f;
    for (int dy = 0; dy < 3; dy++)
      for (int dx = 0; dx < 3; dx++)
        s += yp[(3 * py + dy) * 269 + 3 * px + dx];
    s_y2[p][py][px] = s * (1.0f / 9.0f);
  }
  __syncthreads();
  for (int idx = tp; idx < 10 * 43; idx += 256) {
    int qy = idx / 43, qx = idx - 43 * qy;
    float a = b22[0];
#pragma unroll
    for (int ky = 0; ky < 3; ky++)
#pragma unroll
      for (int kx = 0; kx < 3; kx++)
        a += w22[ky * 3 + kx] * s_y2[p][2 * qy + ky][2 * qx + 2 * kx];
    s_y3[p][qy][qx] = a;
  }
  __syncthreads();
  if (tp < 36) {
    int uy = tp / 12, ux = tp - 12 * uy;
    float s = 0.f;
    for (int dy = 0; dy < 3; dy++)
      for (int dx = 0; dx < 9; dx++)
        s += s_y3[p][3 * uy + dy][3 * ux + dx];
    s_vf2[p][tp] = s * (1.0f / 27.0f);
  }
  __syncthreads();
  if (t < 36) {
    int u = t / 12, x = t - 12 * u;
    float v1 = s_vf2[0][(2 - u) * 12 + x];
    float v2 = s_vf2[1][(2 - u) * 12 + (x + 1) % 12];
    s_v[t] = 0.5f * (v1 + v2) * 0.1f;  // /TEMP
  }
  __syncthreads();
  if (t == 0) {
    float m = -1e30f;
    for (int i = 0; i < 36; i++) m = fmaxf(m, s_v[i]);
    float s = 0.f;
    for (int i = 0; i < 36; i++) { s_v[i] = expf(s_v[i] - m); s += s_v[i]; }
    s_inv = 1.0f / s;
  }
  __syncthreads();
  if (t < 36) {
    out_vf[b * 36 + t] = s_v[t] * s_inv;
    float m = 0.f;
    for (int e = 0; e < 8; e++)
      if (nav_idx[b * 8 + e] == t) m = 1.0f;
    out_mask[b * 36 + t] = m;
  }
}

// ============ kernel 5: LSTM cell (256 blocks: 2 hidden units each) ============
// 256 th = 16 batches x (4 gates x 2 units x 2 k-chunks); shfl_xor(16) reduce.
__global__ __launch_bounds__(256) void k_lstm(
    const float* __restrict__ ctx, const float* __restrict__ vf,
    const float* __restrict__ dfa, const float* __restrict__ pre,
    const float* __restrict__ h0, const float* __restrict__ c0,
    const float* __restrict__ wih, const float* __restrict__ whh,
    const float* __restrict__ bih, const float* __restrict__ bhh,
    float* __restrict__ h1, float* __restrict__ c1) {
  __shared__ float s_cat[B][593];
  __shared__ float s_g[8][16];
  int t = threadIdx.x;
  int u0 = blockIdx.x * 2;
  for (int idx = t; idx < B * 589; idx += 256) {
    int b = idx / 589, k = idx - 589 * b;
    float v;
    if (k < 512) v = ctx[b * 512 + k];
    else if (k < 548) v = vf[b * 36 + (k - 512)];
    else if (k < 552) v = dfa[b * 4 + (k - 548)];
    else v = pre[b * 37 + (k - 552)];
    s_cat[b][k] = v;
  }
  __syncthreads();
  int b = t & 15;
  int slot = t >> 4;                  // 0..15
  int gate = slot >> 2, du = (slot >> 1) & 1, kc = slot & 1;
  int j = gate * 512 + u0 + du;
  const float* wi = wih + (size_t)j * 589;
  const float* cb = s_cat[b];
  float acc = 0.f;
  int k0 = kc ? 295 : 0, k1 = kc ? 589 : 295;
  for (int k = k0; k < k1; k++) acc += cb[k] * wi[k];
  const float* wh = whh + (size_t)j * 512;
  const float* hb = h0 + b * 512;
  int m0 = kc << 8;
  for (int k = m0; k < m0 + 256; k++) acc += hb[k] * wh[k];
  acc += __shfl_xor(acc, 16);
  if (kc == 0) s_g[gate * 2 + du][b] = acc + bih[j] + bhh[j];
  __syncthreads();
  if (t < 32) {
    int bb = t & 15, du2 = t >> 4;    // 0..1
    float gi = s_g[0 + du2][bb], gf = s_g[2 + du2][bb];
    float gg = s_g[4 + du2][bb], go = s_g[6 + du2][bb];
    int u = u0 + du2;
    float c_old = c0[bb * 512 + u];
    float si = 1.0f / (1.0f + expf(-gi));
    float sf = 1.0f / (1.0f + expf(-gf));
    float so = 1.0f / (1.0f + expf(-go));
    float cn = sf * c_old + si * tanhf(gg);
    h1[bb * 512 + u] = so * tanhf(cn);
    c1[bb * 512 + u] = cn;
  }
}

extern "C" void kernel_launch(void* const* d_in, const int* in_sizes, int n_in,
                              void* d_out, int out_size, void* d_ws, size_t ws_size,
                              hipStream_t stream) {
  const float* depth_raw  = (const float*)d_in[0];
  const float* depth_clip = (const float*)d_in[1];
  const float* obj_feat   = (const float*)d_in[2];
  const float* nnf        = (const float*)d_in[3];
  const float* pre        = (const float*)d_in[4];
  const float* h0         = (const float*)d_in[5];
  const float* c0         = (const float*)d_in[6];
  const float* ctx        = (const float*)d_in[7];
  const int*   nav_idx    = (const int*)d_in[8];
  const float* c1w        = (const float*)d_in[9];
  const float* c1b        = (const float*)d_in[10];
  const float* fc1w       = (const float*)d_in[11];
  const float* fc1b       = (const float*)d_in[12];
  const float* fc2w       = (const float*)d_in[13];
  const float* fc2b       = (const float*)d_in[14];
  const float* dynf       = (const float*)d_in[15];
  const float* w21        = (const float*)d_in[16];
  const float* b21        = (const float*)d_in[17];
  const float* w22        = (const float*)d_in[18];
  const float* b22        = (const float*)d_in[19];
  const float* wih        = (const float*)d_in[20];
  const float* whh        = (const float*)d_in[21];
  const float* bih        = (const float*)d_in[22];
  const float* bhh        = (const float*)d_in[23];

  float* ws = (float*)d_ws;
  float* attn   = ws;
  float* dfa    = ws + 576;
  float* y1     = ws + 1792;
  float* cpano  = ws + 552704;

  float* out = (float*)d_out;
  float* out_h1   = out;
  float* out_c1   = out + 8192;
  float* out_vf   = out + 16384;
  float* out_mask = out + 16960;

  k_head<<<B, 128, 0, stream>>>(nnf, ctx, fc1w, fc1b, fc2w, fc2b, attn, dfa);
  k_conv<<<B * NAV * 2, 256, 0, stream>>>(depth_raw, depth_clip, obj_feat,
                                          c1w, c1b, dynf, attn, dfa, cpano);
  k_c21<<<dim3(B, 64), 256, 0, stream>>>(cpano, w21, b21, y1);
  k_tailvf<<<B, 512, 0, stream>>>(y1, w22, b22, nav_idx, out_vf, out_mask);
  k_lstm<<<256, 256, 0, stream>>>(ctx, out_vf, dfa, pre, h0, c0,
                                  wih, whh, bih, bhh, out_h1, out_c1);
}